// Round 6
// baseline (2848.871 us; speedup 1.0000x reference)
//
#include <hip/hip_runtime.h>
#include <hip/hip_bf16.h>
#include <math.h>

#define BSZ   64
#define LSEQ  512
#define EDIM  300
#define HDIM  256
#define TLEN  1023
#define PROJW 512
#define GW    1280

#define NROW  8         // rows per block (row-group)
#define NHID  8         // gate-columns per block
#define RGBLK 32        // blocks (col-slices) per row-group
#define NRG   8
#define NBLK  256
#define SLOTS 2

#define PROJ_N   (BSZ*LSEQ*PROJW)          // 16,777,216 dwords
#define STACKF   PROJ_N
#define STACK_N  (2*BSZ*SLOTS*2*HDIM)      // 131,072 dwords
#define FLAG_OFF (STACKF + STACK_N)
#define FLAGS_N  1024
#define ARR_OFF  (FLAG_OFF + FLAGS_N)
#define ARR_STRIDE 16

#define NODEBIT 0x80000000u
#define SENT    0xFFFFFFFFu
#define LROW    264                        // LDS row stride (dwords)
#define HRO     (NROW*LROW + 4)            // hr-buffer offset (+4 dwords bank shift)
#define RPITCH  328                        // red per-group stride (dwords)
#define RROW    41                         // red per-row stride

// ---------------- Kernel 1: proj = sentence @ W_word + b_word ----------------
__global__ void __launch_bounds__(256)
proj_gemm(const float* __restrict__ A, const float* __restrict__ W,
          const float* __restrict__ bias, float* __restrict__ out) {
    __shared__ float As[8][65];
    __shared__ float Bs[8][64];
    const int tid = threadIdx.x;
    const int tx = tid & 15, ty = tid >> 4;
    const int bm = blockIdx.y, bn = blockIdx.x;

    float acc[4][4] = {};
    const int e  = tid * 2;
    const int ar = e >> 3, ac = e & 7;
    const int br = e >> 6, bc = e & 63;

    for (int k0 = 0; k0 < EDIM; k0 += 8) {
        __syncthreads();
        {
            const float* Ap = A + (size_t)(bm * 64 + ar) * EDIM;
            int gk = k0 + ac;
            As[ac][ar]     = (gk     < EDIM) ? Ap[gk]     : 0.f;
            As[ac + 1][ar] = (gk + 1 < EDIM) ? Ap[gk + 1] : 0.f;
            int gkb = k0 + br;
            float w0 = 0.f, w1 = 0.f;
            if (gkb < EDIM) {
                const float* Wp = W + (size_t)gkb * PROJW + bn * 64;
                w0 = Wp[bc]; w1 = Wp[bc + 1];
            }
            Bs[br][bc] = w0; Bs[br][bc + 1] = w1;
        }
        __syncthreads();
        #pragma unroll
        for (int kk = 0; kk < 8; ++kk) {
            float a[4], b[4];
            #pragma unroll
            for (int i = 0; i < 4; ++i) a[i] = As[kk][ty * 4 + i];
            #pragma unroll
            for (int j = 0; j < 4; ++j) b[j] = Bs[kk][tx * 4 + j];
            #pragma unroll
            for (int i = 0; i < 4; ++i)
                #pragma unroll
                for (int j = 0; j < 4; ++j)
                    acc[i][j] += a[i] * b[j];
        }
    }
    #pragma unroll
    for (int i = 0; i < 4; ++i) {
        const int row  = bm * 64 + ty * 4 + i;
        const int col0 = bn * 64 + tx * 4;
        float* op = out + (size_t)row * PROJW + col0;
        #pragma unroll
        for (int j = 0; j < 4; ++j) op[j] = acc[i][j] + bias[col0 + j];
    }
}

// ------------- Kernel 2: per-step "any row reduces" flags --------------------
__global__ void flags_kernel(const int* __restrict__ trans, int* __restrict__ flags) {
    const int t = blockIdx.x * 256 + threadIdx.x;
    if (t >= TLEN) return;
    int f = 0;
    for (int b = 0; b < BSZ; ++b) f |= (trans[(size_t)b * TLEN + t] != 3) ? 1 : 0;
    flags[t] = f;
}

// ------------- helpers -------------------------------------------------------
__device__ __forceinline__ unsigned encodeH(short tag, int slot, int grow) {
    if (tag >= 0)  return (unsigned)(((size_t)grow * LSEQ + (int)tag) * PROJW);
    if (tag <= -3) return SENT;
    const int par = (tag == -2) ? 1 : 0;
    return NODEBIT | (unsigned)(STACKF + ((par * BSZ + grow) * SLOTS + slot) * (2 * HDIM));
}

__device__ __forceinline__ float cohLoad(const float* ws, unsigned off) {
    return __uint_as_float(__hip_atomic_load((const unsigned*)ws + off,
                          __ATOMIC_RELAXED, __HIP_MEMORY_SCOPE_AGENT));
}
__device__ __forceinline__ float2 cohLoad2(const float* ws, unsigned off) {
    unsigned long long v = __hip_atomic_load((const unsigned long long*)(ws + off),
                          __ATOMIC_RELAXED, __HIP_MEMORY_SCOPE_AGENT);
    union { unsigned long long u; float2 f; } cv; cv.u = v;
    return cv.f;
}
__device__ __forceinline__ void cohStore(float* ws, unsigned off, float v) {
    __hip_atomic_store((unsigned*)ws + off, __float_as_uint(v),
                       __ATOMIC_RELAXED, __HIP_MEMORY_SCOPE_AGENT);
}

__device__ __forceinline__ float loadC(const float* ws, unsigned oh, int gn) {
    if (oh == SENT) return 0.f;
    if (oh & NODEBIT) return cohLoad(ws, (oh & ~NODEBIT) + HDIM + gn);
    return ws[oh + HDIM + gn];
}

// quad swizzle: spreads banks over row AND k-group (both write and read sides)
__device__ __forceinline__ int qswz(int Q, int row) {
    return Q ^ row ^ ((Q >> 3) & 7);
}

// staging: srow = tid>>5 (8 rows), sc = tid&31, quads {sc, sc+32}
__device__ __forceinline__ void stage_rows(float* __restrict__ buf,
    const unsigned* __restrict__ desc, const int* __restrict__ isred,
    const float* __restrict__ ws, int srow, int sc, bool nodePhase) {
    if (!isred[srow]) return;
    const unsigned oh = desc[srow];
    if (!nodePhase) {
        if (oh == SENT) {
            const float4 z = make_float4(0.f, 0.f, 0.f, 0.f);
            #pragma unroll
            for (int j = 0; j < 2; ++j) {
                const int Q = sc + 32 * j;
                *(float4*)&buf[srow * LROW + 4 * qswz(Q, srow)] = z;
            }
        } else if (!(oh & NODEBIT)) {
            const float4* s = (const float4*)(ws + oh);
            #pragma unroll
            for (int j = 0; j < 2; ++j) {
                const int Q = sc + 32 * j;
                *(float4*)&buf[srow * LROW + 4 * qswz(Q, srow)] = s[Q];
            }
        }
    } else if (oh != SENT && (oh & NODEBIT)) {
        const unsigned base = oh & ~NODEBIT;
        #pragma unroll
        for (int j = 0; j < 2; ++j) {
            const int Q = sc + 32 * j;
            const float2 lo = cohLoad2(ws, base + 4 * Q);
            const float2 hi = cohLoad2(ws, base + 4 * Q + 2);
            *(float4*)&buf[srow * LROW + 4 * qswz(Q, srow)] = make_float4(lo.x, lo.y, hi.x, hi.y);
        }
    }
}

// ------------- Kernel 3: cooperative scan (256 blocks, 1 per CU) -------------
__global__ void __launch_bounds__(256, 1)
scan_coop(const int* __restrict__ trans,
          const float* __restrict__ Wl, const float* __restrict__ Wr,
          const float* __restrict__ bred,
          float* __restrict__ ws, float* __restrict__ out) {
    __shared__ __align__(16) float hbuf[HRO + NROW * LROW];   // hl | pad | hr (~17 KB)
    __shared__ __align__(16) float red[16 * RPITCH];          // 21 KB k-split partials
    __shared__ unsigned tbits[NROW][32];
    __shared__ unsigned fbits[32];
    __shared__ short    tg[NROW][SLOTS];
    __shared__ unsigned d_hl[NROW], d_hr[NROW], d_wr[NROW], d_oh[NROW];
    __shared__ int      isred[NROW];

    const int tid   = threadIdx.x;
    // XCD-local mapping: blockIdx % 8 = XCD -> all 32 col-slices of a
    // row-group live on ONE XCD (shared L2 for the redundant word staging).
    const int rg    = blockIdx.x & 7;      // row-group
    const int cs    = blockIdx.x >> 3;     // col-slice
    const int rbase = rg * NROW;
    const int n0    = cs * NHID;

    const int srow = tid >> 5, sc = tid & 31;   // staging map
    const int colq = tid & 7;                   // gemm: gate-col
    const int rh   = (tid >> 3) & 1;            // gemm: row half (rows rh*4..rh*4+3)
    const int m    = (tid >> 4) & 1;            // gemm: matrix (0=left/hl, 1=right/hr)
    const int w8   = tid >> 5;                  // gemm: k-group (8 quads = 32 k)
    const int gn   = n0 + colq;

    const int* flags  = (const int*)(ws + FLAG_OFF);
    unsigned*  arr    = (unsigned*)(ws + ARR_OFF);
    unsigned*  myslot = &arr[(size_t)blockIdx.x * ARR_STRIDE];

    // ---- weight slice into REGISTERS (once): 40 float4 = 160 VGPR ----
    float4 w[8][5];
    {
        const float* src = (m == 0) ? Wl : Wr;
        const int kbase = w8 * 32;
        #pragma unroll
        for (int j = 0; j < 8; ++j) {
            const int k0 = kbase + j * 4;
            #pragma unroll
            for (int g = 0; g < 5; ++g) {
                w[j][g].x = src[(size_t)(k0 + 0) * GW + g * HDIM + gn];
                w[j][g].y = src[(size_t)(k0 + 1) * GW + g * HDIM + gn];
                w[j][g].z = src[(size_t)(k0 + 2) * GW + g * HDIM + gn];
                w[j][g].w = src[(size_t)(k0 + 3) * GW + g * HDIM + gn];
            }
        }
    }
    // Pin the weight values in VGPRs: opaque asm makes rematerialization
    // impossible, so the compiler cannot re-load them inside the t-loop.
    #pragma unroll
    for (int j = 0; j < 8; ++j)
        #pragma unroll
        for (int g = 0; g < 5; ++g)
            asm volatile("" : "+v"(w[j][g].x), "+v"(w[j][g].y),
                              "+v"(w[j][g].z), "+v"(w[j][g].w));

    // ---- transition / flag bitmasks ----
    if (tid < NROW * 32) {
        const int r2 = tid >> 5, wd = tid & 31;
        unsigned bits = 0;
        for (int j = 0; j < 32; ++j) {
            const int t = wd * 32 + j;
            if (t < TLEN && trans[(size_t)(rbase + r2) * TLEN + t] == 3) bits |= (1u << j);
        }
        tbits[r2][wd] = bits;
    }
    if (tid < 32) {
        unsigned bits = 0;
        for (int j = 0; j < 32; ++j) {
            const int t = tid * 32 + j;
            if (t < TLEN && flags[t]) bits |= (1u << j);
        }
        fbits[tid] = bits;
    }
    if (tid < NROW) {
        tg[tid][0] = -3; tg[tid][1] = -3;
        isred[tid] = 0;
    }

    float bv[5];
    #pragma unroll
    for (int g = 0; g < 5; ++g) bv[g] = bred[g * HDIM + gn];

    int ptr = 0, bp = 0;       // controller state (thread tid<NROW owns row tid)
    unsigned nbar = 0;
    __syncthreads();

    for (int t = 0; t < TLEN; ++t) {
        if (tid < NROW) {
            const int r = tid, grow = rbase + r;
            const int is_shift = (tbits[r][t >> 5] >> (t & 31)) & 1;
            if (is_shift) {
                int pos = ptr; if (pos < 0) pos = 0; if (pos > SLOTS - 1) pos = SLOTS - 1;
                tg[r][pos] = (short)min(bp, LSEQ - 1);
                ptr++; bp++;
                isred[r] = 0;
            } else {
                const int i1 = min(max(ptr - 1, 0), SLOTS - 1);
                const int i2 = min(max(ptr - 2, 0), SLOTS - 1);
                const short t1 = tg[r][i1], t2 = tg[r][i2];
                d_hl[r] = encodeH(t2, i2, grow);
                d_hr[r] = encodeH(t1, i1, grow);
                const int pnew = (t2 == -1) ? 1 : 0;
                d_wr[r] = (unsigned)(STACKF + ((pnew * BSZ + grow) * SLOTS + i2) * (2 * HDIM));
                tg[r][i2] = (short)(pnew ? -2 : -1);
                ptr--;
                isred[r] = 1;
            }
        }
        __syncthreads();

        if (!((fbits[t >> 5] >> (t & 31)) & 1)) continue;
        ++nbar;

        // ---- pre-wait staging: zero/word sources (cached path) ----
        stage_rows(hbuf,       d_hl, isred, ws, srow, sc, false);
        stage_rows(hbuf + HRO, d_hr, isred, ws, srow, sc, false);

        // ---- wait for previous reduce-step (rg-local 32 slots) ----
        if (tid < RGBLK) {
            const unsigned* slot = &arr[(size_t)(tid * NRG + rg) * ARR_STRIDE];
            while (__hip_atomic_load(slot, __ATOMIC_RELAXED, __HIP_MEMORY_SCOPE_AGENT) < nbar - 1)
                __builtin_amdgcn_s_sleep(1);
        }
        __syncthreads();

        // ---- post-wait staging: node sources (coherent path) ----
        stage_rows(hbuf,       d_hl, isred, ws, srow, sc, true);
        stage_rows(hbuf + HRO, d_hr, isred, ws, srow, sc, true);
        __syncthreads();

        // ---- prefetch cell-state inputs for finalize (hides L3 latency) ----
        float cl = 0.f, cr = 0.f;
        if (tid < 64) {
            const int orow = tid >> 3;
            if (isred[orow]) {
                cl = loadC(ws, d_hl[orow], gn);
                cr = loadC(ws, d_hr[orow], gn);
            }
        }

        // ---- GEMM: register weights; thread = (colq, rh, m, w8) ----
        float acc[4][5];
        #pragma unroll
        for (int r = 0; r < 4; ++r)
            #pragma unroll
            for (int g = 0; g < 5; ++g) acc[r][g] = 0.f;

        {
            const float* hb = hbuf + m * HRO;
            #pragma unroll
            for (int j = 0; j < 8; ++j) {
                const int kq = w8 * 8 + j;
                #pragma unroll
                for (int r = 0; r < 4; ++r) {
                    const int row = rh * 4 + r;
                    const float4 x = *(const float4*)&hb[row * LROW + 4 * qswz(kq, row)];
                    #pragma unroll
                    for (int g = 0; g < 5; ++g)
                        acc[r][g] += x.x * w[j][g].x + x.y * w[j][g].y
                                   + x.z * w[j][g].z + x.w * w[j][g].w;
                }
            }
        }

        // ---- k-split partials to LDS: group g16 = w8*2+m ----
        {
            const int g16 = w8 * 2 + m;
            #pragma unroll
            for (int r = 0; r < 4; ++r) {
                const int row = rh * 4 + r;
                #pragma unroll
                for (int g = 0; g < 5; ++g)
                    red[g16 * RPITCH + row * RROW + colq * 5 + g] = acc[r][g];
            }
        }
        __syncthreads();

        // ---- finalize + arrival: wave 0 only ----
        if (tid < 64) {
            const int orow = tid >> 3;
            if (isred[orow]) {
                float s[5];
                #pragma unroll
                for (int g = 0; g < 5; ++g) s[g] = bv[g];
                #pragma unroll
                for (int q = 0; q < 16; ++q)
                    #pragma unroll
                    for (int g = 0; g < 5; ++g)
                        s[g] += red[q * RPITCH + orow * RROW + colq * 5 + g];
                const float si = 1.f / (1.f + expf(-s[0]));
                const float sl = 1.f / (1.f + expf(-s[1]));
                const float sr = 1.f / (1.f + expf(-s[2]));
                const float so = 1.f / (1.f + expf(-s[3]));
                const float c_red = sl * cl + sr * cr + si * tanhf(s[4]);
                const float h_red = so * tanhf(c_red);
                cohStore(ws, d_wr[orow] + gn, h_red);
                cohStore(ws, d_wr[orow] + HDIM + gn, c_red);
            }
            asm volatile("s_waitcnt vmcnt(0)" ::: "memory");
            if (tid == 0)
                __hip_atomic_store(myslot, nbar, __ATOMIC_RELAXED, __HIP_MEMORY_SCOPE_AGENT);
        }
        // waves 1-3 run ahead; next controller __syncthreads re-converges
    }

    // ---- final visibility + output ----
    if (tid < RGBLK) {
        const unsigned* slot = &arr[(size_t)(tid * NRG + rg) * ARR_STRIDE];
        while (__hip_atomic_load(slot, __ATOMIC_RELAXED, __HIP_MEMORY_SCOPE_AGENT) < nbar)
            __builtin_amdgcn_s_sleep(1);
    }
    __syncthreads();
    if (tid < NROW) {
        const int top = min(max(ptr - 1, 0), SLOTS - 1);
        d_oh[tid] = encodeH(tg[tid][top], top, rbase + tid);
    }
    __syncthreads();
    if (tid < 64) {
        const int orow = tid >> 3;
        const unsigned oh = d_oh[orow];
        float v;
        if (oh == SENT) v = 0.f;
        else if (oh & NODEBIT) v = cohLoad(ws, (oh & ~NODEBIT) + gn);
        else v = ws[oh + gn];
        out[(size_t)(rbase + orow) * HDIM + gn] = v;
    }
}

// ---------------- Host launch ----------------
extern "C" void kernel_launch(void* const* d_in, const int* in_sizes, int n_in,
                              void* d_out, int out_size, void* d_ws, size_t ws_size,
                              hipStream_t stream) {
    const float* sentence    = (const float*)d_in[0];
    const int*   transitions = (const int*)  d_in[1];
    const float* W_word      = (const float*)d_in[2];
    const float* b_word      = (const float*)d_in[3];
    const float* W_left      = (const float*)d_in[4];
    const float* W_right     = (const float*)d_in[5];
    const float* b_reduce    = (const float*)d_in[6];
    float* out  = (float*)d_out;
    float* ws_f = (float*)d_ws;

    // ws (dwords): [proj 16.78M][stack 131K][flags 1K][barrier 4K] = 67.7 MB
    hipMemsetAsync((char*)d_ws + (size_t)ARR_OFF * 4, 0,
                   (size_t)NBLK * ARR_STRIDE * 4, stream);

    flags_kernel<<<(TLEN + 255) / 256, 256, 0, stream>>>(
        transitions, (int*)(ws_f + FLAG_OFF));

    dim3 g1(PROJW / 64, (BSZ * LSEQ) / 64);
    proj_gemm<<<g1, 256, 0, stream>>>(sentence, W_word, b_word, ws_f);

    scan_coop<<<NBLK, 256, 0, stream>>>(transitions, W_left, W_right, b_reduce,
                                        ws_f, out);
}

// Round 7
// 2817.962 us; speedup vs baseline: 1.0110x; 1.0110x over previous
//
#include <hip/hip_runtime.h>
#include <hip/hip_bf16.h>
#include <math.h>

#define BSZ   64
#define LSEQ  512
#define EDIM  300
#define HDIM  256
#define TLEN  1023
#define PROJW 512
#define GW    1280

#define NROW  8         // rows per block (row-group)
#define NHID  8         // gate-columns per block
#define NRG   8
#define NBLK  256
#define SLOTS 2

#define PROJ_N   (BSZ*LSEQ*PROJW)          // 16,777,216 dwords
#define STACKF   PROJ_N                    // pair region base (dwords)
#define PAIRB    (STACKF/2)                // pair region base (8B pair units)
#define PAIR_N   (2*BSZ*SLOTS*HDIM)        // 65,536 pairs = 131,072 dwords... x2 par
// pairs: [par2][row64][slot2][col256] -> 2*64*2*256 = 65536 pairs = 524288 dwords? no:
// idx = ((par*BSZ+row)*SLOTS+slot)*HDIM + col ; max = 2*64*2*256 = 65536 pairs
#define PAIR_CNT (2*BSZ*SLOTS*HDIM)        // 65,536 pairs = 512 KB

#define NODEBIT 0x80000000u
#define SENT    0xFFFFFFFFu
#define LROW    264                        // LDS row stride (dwords)
#define HRO     (NROW*LROW + 4)            // hr-buffer offset
#define RPITCH  328                        // red per-group stride (dwords)
#define RROW    41                         // red per-row stride

// ---------------- Kernel 1: proj = sentence @ W_word + b_word ----------------
__global__ void __launch_bounds__(256)
proj_gemm(const float* __restrict__ A, const float* __restrict__ W,
          const float* __restrict__ bias, float* __restrict__ out) {
    __shared__ float As[8][65];
    __shared__ float Bs[8][64];
    const int tid = threadIdx.x;
    const int tx = tid & 15, ty = tid >> 4;
    const int bm = blockIdx.y, bn = blockIdx.x;

    float acc[4][4] = {};
    const int e  = tid * 2;
    const int ar = e >> 3, ac = e & 7;
    const int br = e >> 6, bc = e & 63;

    for (int k0 = 0; k0 < EDIM; k0 += 8) {
        __syncthreads();
        {
            const float* Ap = A + (size_t)(bm * 64 + ar) * EDIM;
            int gk = k0 + ac;
            As[ac][ar]     = (gk     < EDIM) ? Ap[gk]     : 0.f;
            As[ac + 1][ar] = (gk + 1 < EDIM) ? Ap[gk + 1] : 0.f;
            int gkb = k0 + br;
            float w0 = 0.f, w1 = 0.f;
            if (gkb < EDIM) {
                const float* Wp = W + (size_t)gkb * PROJW + bn * 64;
                w0 = Wp[bc]; w1 = Wp[bc + 1];
            }
            Bs[br][bc] = w0; Bs[br][bc + 1] = w1;
        }
        __syncthreads();
        #pragma unroll
        for (int kk = 0; kk < 8; ++kk) {
            float a[4], b[4];
            #pragma unroll
            for (int i = 0; i < 4; ++i) a[i] = As[kk][ty * 4 + i];
            #pragma unroll
            for (int j = 0; j < 4; ++j) b[j] = Bs[kk][tx * 4 + j];
            #pragma unroll
            for (int i = 0; i < 4; ++i)
                #pragma unroll
                for (int j = 0; j < 4; ++j)
                    acc[i][j] += a[i] * b[j];
        }
    }
    #pragma unroll
    for (int i = 0; i < 4; ++i) {
        const int row  = bm * 64 + ty * 4 + i;
        const int col0 = bn * 64 + tx * 4;
        float* op = out + (size_t)row * PROJW + col0;
        #pragma unroll
        for (int j = 0; j < 4; ++j) op[j] = acc[i][j] + bias[col0 + j];
    }
}

// ------------- helpers -------------------------------------------------------
__device__ __forceinline__ int qswz(int Q, int row) {
    return Q ^ row ^ ((Q >> 3) & 7);
}

// ------------- Kernel 2: cooperative scan, dataflow sync via epochs ----------
__global__ void __launch_bounds__(256, 1)
scan_coop(const int* __restrict__ trans,
          const float* __restrict__ Wl, const float* __restrict__ Wr,
          const float* __restrict__ bred,
          float* __restrict__ ws, float* __restrict__ out) {
    __shared__ __align__(16) float hbuf[HRO + NROW * LROW];   // hl | pad | hr
    __shared__ __align__(16) float red[16 * RPITCH];          // k-split partials
    __shared__ float    cstk[2 * SLOTS * NROW * NHID];        // private cell stack (1KB)
    __shared__ unsigned tbits[NROW][32];
    __shared__ unsigned fbits[32];
    __shared__ short    tg[NROW][SLOTS];
    __shared__ unsigned eps[NROW][SLOTS];                     // epoch of slot content
    __shared__ unsigned d_hl[NROW], d_hr[NROW], d_wr[NROW];
    __shared__ unsigned e_hl[NROW], e_hr[NROW];
    __shared__ unsigned c_l[NROW], c_r[NROW], cw[NROW];
    __shared__ unsigned d_oh[NROW], e_oh[NROW];
    __shared__ int      isred[NROW];

    const int tid   = threadIdx.x;
    // XCD-local mapping: blockIdx % 8 = XCD -> one row-group per XCD.
    const int rg    = blockIdx.x & 7;      // row-group
    const int cs    = blockIdx.x >> 3;     // col-slice
    const int rbase = rg * NROW;
    const int n0    = cs * NHID;

    const int srow = tid >> 5, sc = tid & 31;   // staging map
    const int colq = tid & 7;                   // gemm: gate-col
    const int rh   = (tid >> 3) & 1;            // gemm: row half
    const int m    = (tid >> 4) & 1;            // gemm: matrix (0=hl, 1=hr)
    const int w8   = tid >> 5;                  // gemm: k-group
    const int gn   = n0 + colq;
    const int orow = tid >> 3;                  // finalize row (tid<64)

    unsigned long long* p64 = (unsigned long long*)ws;

    // ---- weight slice into REGISTERS (once) ----
    float4 w[8][5];
    {
        const float* src = (m == 0) ? Wl : Wr;
        const int kbase = w8 * 32;
        #pragma unroll
        for (int j = 0; j < 8; ++j) {
            const int k0 = kbase + j * 4;
            #pragma unroll
            for (int g = 0; g < 5; ++g) {
                w[j][g].x = src[(size_t)(k0 + 0) * GW + g * HDIM + gn];
                w[j][g].y = src[(size_t)(k0 + 1) * GW + g * HDIM + gn];
                w[j][g].z = src[(size_t)(k0 + 2) * GW + g * HDIM + gn];
                w[j][g].w = src[(size_t)(k0 + 3) * GW + g * HDIM + gn];
            }
        }
    }
    #pragma unroll
    for (int j = 0; j < 8; ++j)
        #pragma unroll
        for (int g = 0; g < 5; ++g)
            asm volatile("" : "+v"(w[j][g].x), "+v"(w[j][g].y),
                              "+v"(w[j][g].z), "+v"(w[j][g].w));

    // ---- transition bitmasks (shift=1) ----
    if (tid < NROW * 32) {
        const int r2 = tid >> 5, wd = tid & 31;
        unsigned bits = 0;
        for (int j = 0; j < 32; ++j) {
            const int t = wd * 32 + j;
            if (t < TLEN && trans[(size_t)(rbase + r2) * TLEN + t] == 3) bits |= (1u << j);
        }
        tbits[r2][wd] = bits;
    }
    if (tid < NROW) {
        tg[tid][0] = -3; tg[tid][1] = -3;
        eps[tid][0] = 0; eps[tid][1] = 0;
        isred[tid] = 0;
    }
    __syncthreads();
    if (tid < 32) {   // rg-local "any reduce at step t" bits
        unsigned fb = 0;
        #pragma unroll
        for (int r2 = 0; r2 < NROW; ++r2) fb |= ~tbits[r2][tid];
        if (tid == 31) fb &= 0x7FFFFFFFu;   // t=1023 invalid
        fbits[tid] = fb;
    }

    float bv[5];
    #pragma unroll
    for (int g = 0; g < 5; ++g) bv[g] = bred[g * HDIM + gn];

    int ptr = 0, bp = 0;       // controller state (thread tid<NROW owns row tid)
    unsigned nbar = 0;
    __syncthreads();

    for (int t = 0; t < TLEN; ++t) {
        const int redstep = (fbits[t >> 5] >> (t & 31)) & 1;
        if (redstep) ++nbar;

        if (tid < NROW) {
            const int r = tid, grow = rbase + r;
            const int is_shift = (tbits[r][t >> 5] >> (t & 31)) & 1;
            if (is_shift) {
                int pos = ptr; if (pos < 0) pos = 0; if (pos > SLOTS - 1) pos = SLOTS - 1;
                tg[r][pos] = (short)min(bp, LSEQ - 1);
                ptr++; bp++;
                isred[r] = 0;
            } else {
                const int i1 = min(max(ptr - 1, 0), SLOTS - 1);
                const int i2 = min(max(ptr - 2, 0), SLOTS - 1);
                const short t1 = tg[r][i1], t2 = tg[r][i2];
                // left child
                unsigned dl, el = 0, cdl;
                if (t2 >= 0)       { dl = (unsigned)((grow * LSEQ + (int)t2) * PROJW); cdl = dl + HDIM; }
                else if (t2 <= -3) { dl = SENT; cdl = SENT; }
                else { const int par = (t2 == -2);
                       dl = NODEBIT | (unsigned)(PAIRB + ((par * BSZ + grow) * SLOTS + i2) * HDIM);
                       el = eps[r][i2];
                       cdl = NODEBIT | (unsigned)(par * 2 + i2); }
                // right child
                unsigned dr, er = 0, cdr;
                if (t1 >= 0)       { dr = (unsigned)((grow * LSEQ + (int)t1) * PROJW); cdr = dr + HDIM; }
                else if (t1 <= -3) { dr = SENT; cdr = SENT; }
                else { const int par = (t1 == -2);
                       dr = NODEBIT | (unsigned)(PAIRB + ((par * BSZ + grow) * SLOTS + i1) * HDIM);
                       er = eps[r][i1];
                       cdr = NODEBIT | (unsigned)(par * 2 + i1); }
                d_hl[r] = dl; e_hl[r] = el; c_l[r] = cdl;
                d_hr[r] = dr; e_hr[r] = er; c_r[r] = cdr;
                const int pnew = (t2 == -1) ? 1 : 0;
                d_wr[r] = (unsigned)(PAIRB + ((pnew * BSZ + grow) * SLOTS + i2) * HDIM);
                cw[r]   = (unsigned)(pnew * 2 + i2);
                eps[r][i2] = nbar;
                tg[r][i2] = (short)(pnew ? -2 : -1);
                ptr--;
                isred[r] = 1;
            }
        }
        __syncthreads();

        if (!redstep) continue;

        // ---- staging: words cached, nodes epoch-polled (both buffers) ----
        if (isred[srow]) {
            #pragma unroll
            for (int buf = 0; buf < 2; ++buf) {
                float* hb = hbuf + buf * HRO;
                const unsigned oh = buf ? d_hr[srow] : d_hl[srow];
                const unsigned ee = buf ? e_hr[srow] : e_hl[srow];
                float h[8];
                if (oh == SENT) {
                    #pragma unroll
                    for (int i = 0; i < 8; ++i) h[i] = 0.f;
                } else if (!(oh & NODEBIT)) {
                    const float4 a = *(const float4*)(ws + oh + sc * 8);
                    const float4 b = *(const float4*)(ws + oh + sc * 8 + 4);
                    h[0]=a.x; h[1]=a.y; h[2]=a.z; h[3]=a.w;
                    h[4]=b.x; h[5]=b.y; h[6]=b.z; h[7]=b.w;
                } else {
                    const unsigned pb = (oh & ~NODEBIT) + sc * 8;
                    unsigned long long v[8];
                    for (;;) {
                        #pragma unroll
                        for (int i = 0; i < 8; ++i)
                            v[i] = __hip_atomic_load(p64 + pb + i,
                                     __ATOMIC_RELAXED, __HIP_MEMORY_SCOPE_AGENT);
                        bool ok = true;
                        #pragma unroll
                        for (int i = 0; i < 8; ++i)
                            ok &= ((unsigned)(v[i] >> 32) >= ee);
                        if (ok) break;
                        __builtin_amdgcn_s_sleep(1);
                    }
                    #pragma unroll
                    for (int i = 0; i < 8; ++i) h[i] = __uint_as_float((unsigned)v[i]);
                }
                *(float4*)&hb[srow * LROW + 4 * qswz(2 * sc + 0, srow)] =
                    make_float4(h[0], h[1], h[2], h[3]);
                *(float4*)&hb[srow * LROW + 4 * qswz(2 * sc + 1, srow)] =
                    make_float4(h[4], h[5], h[6], h[7]);
            }
        }
        __syncthreads();

        // ---- prefetch word-path cell inputs (plain cached loads) ----
        float clw = 0.f, crw = 0.f;
        if (tid < 64 && isred[orow]) {
            const unsigned cdl = c_l[orow], cdr = c_r[orow];
            if (cdl != SENT && !(cdl & NODEBIT)) clw = ws[cdl + gn];
            if (cdr != SENT && !(cdr & NODEBIT)) crw = ws[cdr + gn];
        }

        // ---- GEMM: register weights; thread = (colq, rh, m, w8) ----
        float acc[4][5];
        #pragma unroll
        for (int r = 0; r < 4; ++r)
            #pragma unroll
            for (int g = 0; g < 5; ++g) acc[r][g] = 0.f;
        {
            const float* hb = hbuf + m * HRO;
            #pragma unroll
            for (int j = 0; j < 8; ++j) {
                const int kq = w8 * 8 + j;
                #pragma unroll
                for (int r = 0; r < 4; ++r) {
                    const int row = rh * 4 + r;
                    const float4 x = *(const float4*)&hb[row * LROW + 4 * qswz(kq, row)];
                    #pragma unroll
                    for (int g = 0; g < 5; ++g)
                        acc[r][g] += x.x * w[j][g].x + x.y * w[j][g].y
                                   + x.z * w[j][g].z + x.w * w[j][g].w;
                }
            }
        }
        {
            const int g16 = w8 * 2 + m;
            #pragma unroll
            for (int r = 0; r < 4; ++r) {
                const int row = rh * 4 + r;
                #pragma unroll
                for (int g = 0; g < 5; ++g)
                    red[g16 * RPITCH + row * RROW + colq * 5 + g] = acc[r][g];
            }
        }
        __syncthreads();

        // ---- finalize: wave 0 only; store (h, epoch) pair, c stays local ----
        if (tid < 64) {
            if (isred[orow]) {
                float s[5];
                #pragma unroll
                for (int g = 0; g < 5; ++g) s[g] = bv[g];
                #pragma unroll
                for (int q = 0; q < 16; ++q)
                    #pragma unroll
                    for (int g = 0; g < 5; ++g)
                        s[g] += red[q * RPITCH + orow * RROW + colq * 5 + g];
                const unsigned cdl = c_l[orow], cdr = c_r[orow];
                const float cl = (cdl == SENT) ? 0.f :
                    ((cdl & NODEBIT) ? cstk[((cdl & 3) * NROW + orow) * NHID + colq] : clw);
                const float cr = (cdr == SENT) ? 0.f :
                    ((cdr & NODEBIT) ? cstk[((cdr & 3) * NROW + orow) * NHID + colq] : crw);
                const float si = 1.f / (1.f + expf(-s[0]));
                const float sl = 1.f / (1.f + expf(-s[1]));
                const float sr = 1.f / (1.f + expf(-s[2]));
                const float so = 1.f / (1.f + expf(-s[3]));
                const float c_red = sl * cl + sr * cr + si * tanhf(s[4]);
                const float h_red = so * tanhf(c_red);
                cstk[(cw[orow] * NROW + orow) * NHID + colq] = c_red;
                const unsigned long long pv =
                    ((unsigned long long)nbar << 32) | (unsigned long long)__float_as_uint(h_red);
                __hip_atomic_store(p64 + d_wr[orow] + gn, pv,
                                   __ATOMIC_RELAXED, __HIP_MEMORY_SCOPE_AGENT);
            }
        }
        // no barrier: epoch-tagged data IS the synchronization
    }

    // ---- output: epoch-poll final stack tops ----
    if (tid < NROW) {
        const int top = min(max(ptr - 1, 0), SLOTS - 1);
        const short tt = tg[tid][top];
        const int grow = rbase + tid;
        if (tt >= 0)       { d_oh[tid] = (unsigned)((grow * LSEQ + (int)tt) * PROJW); e_oh[tid] = 0; }
        else if (tt <= -3) { d_oh[tid] = SENT; e_oh[tid] = 0; }
        else { const int par = (tt == -2);
               d_oh[tid] = NODEBIT | (unsigned)(PAIRB + ((par * BSZ + grow) * SLOTS + top) * HDIM);
               e_oh[tid] = eps[tid][top]; }
    }
    __syncthreads();
    if (tid < 64) {
        const unsigned oh = d_oh[orow];
        float v;
        if (oh == SENT) v = 0.f;
        else if (!(oh & NODEBIT)) v = ws[oh + gn];
        else {
            const unsigned pb = (oh & ~NODEBIT) + gn;
            const unsigned ee = e_oh[orow];
            unsigned long long pv;
            for (;;) {
                pv = __hip_atomic_load(p64 + pb, __ATOMIC_RELAXED, __HIP_MEMORY_SCOPE_AGENT);
                if ((unsigned)(pv >> 32) >= ee) break;
                __builtin_amdgcn_s_sleep(1);
            }
            v = __uint_as_float((unsigned)pv);
        }
        out[(size_t)(rbase + orow) * HDIM + gn] = v;
    }
}

// ---------------- Host launch ----------------
extern "C" void kernel_launch(void* const* d_in, const int* in_sizes, int n_in,
                              void* d_out, int out_size, void* d_ws, size_t ws_size,
                              hipStream_t stream) {
    const float* sentence    = (const float*)d_in[0];
    const int*   transitions = (const int*)  d_in[1];
    const float* W_word      = (const float*)d_in[2];
    const float* b_word      = (const float*)d_in[3];
    const float* W_left      = (const float*)d_in[4];
    const float* W_right     = (const float*)d_in[5];
    const float* b_reduce    = (const float*)d_in[6];
    float* out  = (float*)d_out;
    float* ws_f = (float*)d_ws;

    // ws (dwords): [proj 16.78M][(h,epoch) pairs 128K dwords... 65536 pairs = 512KB]
    // epochs must be cleared every launch (graph replays reuse ws)
    hipMemsetAsync((char*)d_ws + (size_t)STACKF * 4, 0,
                   (size_t)PAIR_CNT * 8, stream);

    dim3 g1(PROJW / 64, (BSZ * LSEQ) / 64);
    proj_gemm<<<g1, 256, 0, stream>>>(sentence, W_word, b_word, ws_f);

    scan_coop<<<NBLK, 256, 0, stream>>>(transitions, W_left, W_right, b_reduce,
                                        ws_f, out);
}